// Round 4
// baseline (624.764 us; speedup 1.0000x reference)
//
#include <hip/hip_runtime.h>

// ---------------------------------------------------------------------------
// Triplane sample + 4-layer MLP, N=1e6 points.
//   prep: K0 zero hist | K1 plane transpose f32->f16(x256) [H][W][C] |
//         K2 weights->f16 | K3 Morton histogram | K4 scan | K5 scatter
//   K6: FUSED sample + MLP. 32 points/wave; lane pairs split channels when
//       sampling; H lives in XOR-swizzled LDS (8 KB/wave, no bank conflicts);
//       MLP via mfma_f32_16x16x32_f16 computed transposed (C^T = W.H^T).
// Scale S=256 keeps f16 in normal range; epilogues add S*b in fp32; final
// layer divides by S in fp32. out[orig_idx] scatter undoes the sort.
// R4 fix: final-layer dot now covers all 128 hidden units (R3 only summed 32:
// per-lane loop was h*8+half*4 dwords => k in [0,32) across the pair).
// ---------------------------------------------------------------------------

#define SF 256.0f

typedef _Float16 half8 __attribute__((ext_vector_type(8)));
typedef float f32x4 __attribute__((ext_vector_type(4)));
typedef unsigned int u32x4 __attribute__((ext_vector_type(4)));
typedef unsigned int u32x2 __attribute__((ext_vector_type(2)));

// ---------------- K0: zero histogram ----------------
__global__ __launch_bounds__(256) void zero_hist(unsigned* __restrict__ hist) {
  int t = blockIdx.x * 256 + threadIdx.x;
  if (t < 32768) hist[t] = 0u;
}

// ---------------- K1: plane transpose+convert+scale ----------------
__global__ __launch_bounds__(256) void plane_transpose(
    const float* __restrict__ planes, _Float16* __restrict__ ph) {
  int t = blockIdx.x * 256 + threadIdx.x;     // 3*2^18 threads exactly
  int pid = t >> 18;
  int rem = t & ((1 << 18) - 1);              // y*512 + x
  const float* src = planes + ((size_t)pid << 23) + rem;  // [pid][c][y][x]
  union { _Float16 h[32]; u32x4 v[4]; } u;
#pragma unroll
  for (int c = 0; c < 32; c++)
    u.h[c] = (_Float16)(src[(size_t)c << 18] * SF);
  u32x4* dst = reinterpret_cast<u32x4*>(ph + ((size_t)t << 5));
#pragma unroll
  for (int i = 0; i < 4; i++) dst[i] = u.v[i];
}

// ---------------- K2: weight f32 -> f16 ----------------
__global__ __launch_bounds__(256) void weights_convert(
    const float* __restrict__ w0, const float* __restrict__ w1,
    const float* __restrict__ w2, _Float16* __restrict__ w0h,
    _Float16* __restrict__ w1h, _Float16* __restrict__ w2h) {
  int t = blockIdx.x * 256 + threadIdx.x;     // 36864 threads exactly
  if (t < 4096) w0h[t] = (_Float16)w0[t];
  else if (t < 20480) w1h[t - 4096] = (_Float16)w1[t - 4096];
  else w2h[t - 20480] = (_Float16)w2[t - 20480];
}

// ---------------- Morton key ----------------
__device__ inline unsigned spread5(unsigned v) {
  v &= 31u;
  v = (v | (v << 8)) & 0x100Fu;
  v = (v | (v << 4)) & 0x10C3u;
  v = (v | (v << 2)) & 0x1249u;
  return v;
}
__device__ inline unsigned cellkey(float x, float y, float z) {
  int qx = min(31, max(0, (int)((x + 1.0f) * 16.0f)));
  int qy = min(31, max(0, (int)((y + 1.0f) * 16.0f)));
  int qz = min(31, max(0, (int)((z + 1.0f) * 16.0f)));
  return spread5((unsigned)qx) | (spread5((unsigned)qy) << 1) |
         (spread5((unsigned)qz) << 2);
}

// ---------------- K3: histogram ----------------
__global__ __launch_bounds__(256) void hist_kernel(
    const float* __restrict__ coords, unsigned* __restrict__ hist, int npts) {
  int p = blockIdx.x * 256 + threadIdx.x;
  if (p >= npts) return;
  float x = coords[3 * (size_t)p + 0];
  float y = coords[3 * (size_t)p + 1];
  float z = coords[3 * (size_t)p + 2];
  atomicAdd(&hist[cellkey(x, y, z)], 1u);
}

// ---------------- K4: exclusive scan of 32768 counts ----------------
__global__ __launch_bounds__(1024) void scan_kernel(
    const unsigned* __restrict__ hist, unsigned* __restrict__ cursor) {
  __shared__ unsigned sums[1024];
  int t = threadIdx.x;
  unsigned local[32];
  unsigned s = 0;
#pragma unroll
  for (int i = 0; i < 32; i++) { local[i] = hist[t * 32 + i]; s += local[i]; }
  sums[t] = s;
  __syncthreads();
  for (int off = 1; off < 1024; off <<= 1) {
    unsigned v = (t >= off) ? sums[t - off] : 0u;
    __syncthreads();
    sums[t] += v;
    __syncthreads();
  }
  unsigned base = (t == 0) ? 0u : sums[t - 1];
#pragma unroll
  for (int i = 0; i < 32; i++) { cursor[t * 32 + i] = base; base += local[i]; }
}

// ---------------- K5: scatter into bucket order ----------------
__global__ __launch_bounds__(256) void scatter_kernel(
    const float* __restrict__ coords, unsigned* __restrict__ cursor,
    float4* __restrict__ sorted, int npts) {
  int p = blockIdx.x * 256 + threadIdx.x;
  if (p >= npts) return;
  float x = coords[3 * (size_t)p + 0];
  float y = coords[3 * (size_t)p + 1];
  float z = coords[3 * (size_t)p + 2];
  unsigned pos = atomicAdd(&cursor[cellkey(x, y, z)], 1u);
  float4 v;
  v.x = x; v.y = y; v.z = z; v.w = __uint_as_float((unsigned)p);
  sorted[pos] = v;
}

// ---------------- K6: fused sample + MLP ----------------
// LDS H layout, per wave: 32 point-rows x 64 dwords (128 f16), XOR-swizzled:
// logical dword kd (=k/2) of point p lives at p*64 + ((c ^ (p&15))<<2) + (kd&3),
// c = kd>>2. Keeps 16B alignment; spreads point-indexed access over all banks.
__device__ inline int hoff(int p, int kd) {
  int c = kd >> 2;
  return (p << 6) + ((((unsigned)(c ^ (p & 15)) & 15u) << 2)) + (kd & 3);
}

__device__ inline half8 ld16g(const _Float16* p) {
  return *reinterpret_cast<const half8*>(p);
}
__device__ inline half8 ld16s(const unsigned* p) {
  return *reinterpret_cast<const half8*>(p);
}

// bilinear tap accumulate: 16 channels starting at ch0
__device__ inline void samp16(const _Float16* __restrict__ pl, float X, float Y,
                              int ch0, float* acc) {
  float fx = (X + 1.0f) * 0.5f * 511.0f;
  float fy = (Y + 1.0f) * 0.5f * 511.0f;
  float x0f = floorf(fx), y0f = floorf(fy);
  float wx1 = fx - x0f, wy1 = fy - y0f;
  float wx0 = 1.0f - wx1, wy0 = 1.0f - wy1;
  int x0 = (int)x0f, y0 = (int)y0f;
  int x1 = x0 + 1, y1 = y0 + 1;
  float vx0 = (x0 >= 0 && x0 < 512) ? 1.0f : 0.0f;
  float vx1 = (x1 >= 0 && x1 < 512) ? 1.0f : 0.0f;
  float vy0 = (y0 >= 0 && y0 < 512) ? 1.0f : 0.0f;
  float vy1 = (y1 >= 0 && y1 < 512) ? 1.0f : 0.0f;
  int xc0 = min(max(x0, 0), 511), xc1 = min(max(x1, 0), 511);
  int yc0 = min(max(y0, 0), 511), yc1 = min(max(y1, 0), 511);
  float w00 = wx0 * wy0 * vx0 * vy0, w10 = wx1 * wy0 * vx1 * vy0;
  float w01 = wx0 * wy1 * vx0 * vy1, w11 = wx1 * wy1 * vx1 * vy1;
  const _Float16* p00 = pl + ((((size_t)yc0 << 9) + xc0) << 5) + ch0;
  const _Float16* p10 = pl + ((((size_t)yc0 << 9) + xc1) << 5) + ch0;
  const _Float16* p01 = pl + ((((size_t)yc1 << 9) + xc0) << 5) + ch0;
  const _Float16* p11 = pl + ((((size_t)yc1 << 9) + xc1) << 5) + ch0;
  union { u32x4 v; _Float16 h[8]; } a0, a1, b0, b1, c0, c1, d0, d1;
  a0.v = *(const u32x4*)(p00); a1.v = *(const u32x4*)(p00 + 8);
  b0.v = *(const u32x4*)(p10); b1.v = *(const u32x4*)(p10 + 8);
  c0.v = *(const u32x4*)(p01); c1.v = *(const u32x4*)(p01 + 8);
  d0.v = *(const u32x4*)(p11); d1.v = *(const u32x4*)(p11 + 8);
#pragma unroll
  for (int j = 0; j < 8; j++) {
    acc[j] += w00 * (float)a0.h[j] + w10 * (float)b0.h[j] +
              w01 * (float)c0.h[j] + w11 * (float)d0.h[j];
    acc[8 + j] += w00 * (float)a1.h[j] + w10 * (float)b1.h[j] +
                  w01 * (float)c1.h[j] + w11 * (float)d1.h[j];
  }
}

// epilogue: C tile (col=point lane&15, rows=hidden quad*4+r [m89]) ->
// relu(acc + S*b) -> f16 pairs -> b64 into swizzled H.
__device__ inline void epilogue2(f32x4 (&acc)[8][2], const float* __restrict__ bias,
                                 unsigned* H, int n16, int g) {
#pragma unroll
  for (int mt = 0; mt < 8; mt++) {
    f32x4 bb = *reinterpret_cast<const f32x4*>(bias + mt * 16 + g * 4);
#pragma unroll
    for (int nt = 0; nt < 2; nt++) {
      union { _Float16 h[4]; u32x2 v; } u;
#pragma unroll
      for (int r = 0; r < 4; r++) {
        float x = acc[mt][nt][r] + SF * bb[r];
        u.h[r] = (_Float16)fmaxf(x, 0.0f);
      }
      *reinterpret_cast<u32x2*>(&H[hoff(nt * 16 + n16, mt * 8 + g * 2)]) = u.v;
    }
  }
}

__device__ inline void layer128s(f32x4 (&acc)[8][2], unsigned* H,
                                 const _Float16* __restrict__ Wg,
                                 const float* __restrict__ bias, int n16, int g) {
  half8 B[2][4];  // fully preloaded before epilogue overwrites H (WAR-safe)
#pragma unroll
  for (int nt = 0; nt < 2; nt++)
#pragma unroll
    for (int ks = 0; ks < 4; ks++)
      B[nt][ks] = ld16s(&H[hoff(nt * 16 + n16, ks * 16 + g * 4)]);
  f32x4 zero = {0.0f, 0.0f, 0.0f, 0.0f};
#pragma unroll
  for (int mt = 0; mt < 8; mt++) {
#pragma unroll
    for (int nt = 0; nt < 2; nt++) acc[mt][nt] = zero;
#pragma unroll
    for (int ks = 0; ks < 4; ks++) {
      half8 A = ld16g(Wg + (mt * 16 + n16) * 128 + ks * 32 + g * 8);
#pragma unroll
      for (int nt = 0; nt < 2; nt++)
        acc[mt][nt] =
            __builtin_amdgcn_mfma_f32_16x16x32_f16(A, B[nt][ks], acc[mt][nt], 0, 0, 0);
    }
  }
  epilogue2(acc, bias, H, n16, g);
}

__global__ __launch_bounds__(256, 3) void fused_kernel(
    const float* __restrict__ coords, const float4* __restrict__ sorted,
    const _Float16* __restrict__ ph, const _Float16* __restrict__ w0h,
    const _Float16* __restrict__ w1h, const _Float16* __restrict__ w2h,
    const float* __restrict__ b0, const float* __restrict__ b1,
    const float* __restrict__ b2, const float* __restrict__ w3,
    const float* __restrict__ b3, float* __restrict__ out, int npts,
    int use_sorted) {
  __shared__ unsigned hbuf[4][2048];  // 32 KB/block; wave-private 8 KB slices
  int tid = threadIdx.x;
  int wv = tid >> 6, lane = tid & 63;
  int n16 = lane & 15, g = lane >> 4;
  // XCD swizzle: contiguous Morton range per XCD for L2 locality.
  int nb = gridDim.x, bid = blockIdx.x;
  int per = nb >> 3;
  int sb = (bid < (per << 3)) ? ((bid & 7) * per + (bid >> 3)) : bid;
  long wbase = (long)sb * 128 + wv * 32;  // 32 points per wave
  if (wbase >= npts) return;              // wave-private LDS: no syncthreads
  unsigned* H = hbuf[wv];

  // ---- sampling: lane pair (2p,2p+1) splits the 32 channels ----
  int p = lane >> 1, h = lane & 1;
  long gp = wbase + p;
  if (gp >= npts) gp = npts - 1;
  float cx, cy, cz;
  unsigned idx;
  if (use_sorted) {
    float4 f = sorted[gp];
    cx = f.x; cy = f.y; cz = f.z;
    idx = __float_as_uint(f.w);
  } else {
    cx = coords[3 * gp + 0];
    cy = coords[3 * gp + 1];
    cz = coords[3 * gp + 2];
    idx = (unsigned)gp;
  }
  float a16[16];
#pragma unroll
  for (int i = 0; i < 16; i++) a16[i] = 0.0f;
  int ch0 = h * 16;
  samp16(ph, cx, cy, ch0, a16);              // plane 0: (x, y)
  samp16(ph + (1u << 23), cy, cz, ch0, a16); // plane 1: (y, z)
  samp16(ph + (2u << 23), cx, cz, ch0, a16); // plane 2: (x, z)
  {
    union { _Float16 hh[16]; u32x4 v[2]; } u;
#pragma unroll
    for (int i = 0; i < 16; i++) u.hh[i] = (_Float16)a16[i];
    *reinterpret_cast<u32x4*>(&H[hoff(p, h * 8)]) = u.v[0];
    *reinterpret_cast<u32x4*>(&H[hoff(p, h * 8 + 4)]) = u.v[1];
  }

  // ---- layer 0: C^T = W0(128x32) * feats^T(32x32) ----
  f32x4 acc[8][2];
  {
    half8 B[2];
#pragma unroll
    for (int nt = 0; nt < 2; nt++)
      B[nt] = ld16s(&H[hoff(nt * 16 + n16, g * 4)]);
    f32x4 zero = {0.0f, 0.0f, 0.0f, 0.0f};
#pragma unroll
    for (int mt = 0; mt < 8; mt++) {
      half8 A = ld16g(w0h + (mt * 16 + n16) * 32 + g * 8);
#pragma unroll
      for (int nt = 0; nt < 2; nt++)
        acc[mt][nt] = __builtin_amdgcn_mfma_f32_16x16x32_f16(A, B[nt], zero, 0, 0, 0);
    }
    epilogue2(acc, b0, H, n16, g);
  }

  layer128s(acc, H, w1h, b1, n16, g);
  layer128s(acc, H, w2h, b2, n16, g);

  // ---- final layer: lane pair splits the 128-dot (64 elems each) ----
  float o = 0.0f;
#pragma unroll
  for (int q = 0; q < 8; q++) {
    half8 hv = ld16s(&H[hoff(p, h * 32 + q * 4)]);  // f16 k = h*64 + q*8 + j
    const float* wp = w3 + h * 64 + q * 8;
#pragma unroll
    for (int j = 0; j < 8; j++) o += (float)hv[j] * wp[j];
  }
  float other = __shfl_xor(o, 1, 64);
  if (h == 0 && wbase + p < npts)
    out[idx] = (o + other) * (1.0f / SF) + b3[0];
}

// ---------------- launch ----------------
extern "C" void kernel_launch(void* const* d_in, const int* in_sizes, int n_in,
                              void* d_out, int out_size, void* d_ws, size_t ws_size,
                              hipStream_t stream) {
  const float* coords = (const float*)d_in[0];
  const float* planes = (const float*)d_in[1];
  const float* w0 = (const float*)d_in[2];
  const float* b0 = (const float*)d_in[3];
  const float* w1 = (const float*)d_in[4];
  const float* b1 = (const float*)d_in[5];
  const float* w2 = (const float*)d_in[6];
  const float* b2 = (const float*)d_in[7];
  const float* w3 = (const float*)d_in[8];
  const float* b3 = (const float*)d_in[9];
  float* out = (float*)d_out;
  int npts = in_sizes[0] / 3;  // 1,000,000

  // workspace layout (bytes):
  //   ph      @ 0          50,331,648
  //   w0h     @ 50331648   8,192
  //   w1h     @ 50339840   32,768
  //   w2h     @ 50372608   32,768
  //   hist    @ 50405376   131,072
  //   cursor  @ 50536448   131,072
  //   sorted  @ 50667520   npts*16
  char* ws = (char*)d_ws;
  _Float16* ph = (_Float16*)ws;
  _Float16* w0h = (_Float16*)(ws + 50331648);
  _Float16* w1h = (_Float16*)(ws + 50339840);
  _Float16* w2h = (_Float16*)(ws + 50372608);
  unsigned* hist = (unsigned*)(ws + 50405376);
  unsigned* cursor = (unsigned*)(ws + 50536448);
  float4* sorted = (float4*)(ws + 50667520);
  size_t need = 50667520 + (size_t)npts * 16;
  int use_sorted = (ws_size == 0 || ws_size >= need) ? 1 : 0;

  int blk = (npts + 255) / 256;
  plane_transpose<<<3072, 256, 0, stream>>>(planes, ph);
  weights_convert<<<144, 256, 0, stream>>>(w0, w1, w2, w0h, w1h, w2h);
  if (use_sorted) {
    zero_hist<<<128, 256, 0, stream>>>(hist);
    hist_kernel<<<blk, 256, 0, stream>>>(coords, hist, npts);
    scan_kernel<<<1, 1024, 0, stream>>>(hist, cursor);
    scatter_kernel<<<blk, 256, 0, stream>>>(coords, cursor, sorted, npts);
  }
  int fblk = (npts + 127) / 128;
  fused_kernel<<<fblk, 256, 0, stream>>>(coords, sorted, ph, w0h, w1h, w2h, b0,
                                         b1, b2, w3, b3, out, npts, use_sorted);
}